// Round 17
// baseline (24.354 us; speedup 1.0000x reference)
//
#include <hip/hip_runtime.h>

#define KS    7
#define RAD   3
#define TW    32            // tile width (output px)
#define TH    16            // tile height
#define HR    22            // halo rows
#define PAIRS 21            // col-pairs per parity row (19 needed, +2 pad)
#define NSITE (HR*2*PAIRS)  // 924 sites
#define H     256
#define W     256
#define HWp   (H*W)
#define NTASK (HR*10*4)     // 880 input staging tasks per group

typedef __fp16    h2raw __attribute__((ext_vector_type(2)));
typedef _Float16  f16x2 __attribute__((ext_vector_type(2)));

__device__ __forceinline__ unsigned pk(float a, float b) {
    h2raw h = __builtin_amdgcn_cvt_pkrtz(a, b);
    return __builtin_bit_cast(unsigned, h);
}
__device__ __forceinline__ f16x2 bch(unsigned u) {
    return __builtin_bit_cast(f16x2, u);
}

#if __has_builtin(__builtin_amdgcn_fdot2)
__device__ __forceinline__ float fdot2(f16x2 a, f16x2 b, float c) {
    return __builtin_amdgcn_fdot2(a, b, c, false);
}
#else
__device__ __forceinline__ float fdot2(f16x2 a, f16x2 b, float c) {
    return c + (float)a.x * (float)b.x + (float)a.y * (float)b.y;
}
#endif

// ---- issue group g's global loads into registers (no LDS touch) ----
#define ISSUE_IN(g) do {                                                    \
    _Pragma("unroll")                                                       \
    for (int j = 0; j < 2; ++j) {                                           \
        int t = tid + j * 512;                                              \
        iA[j] = make_float4(0.f, 0.f, 0.f, 0.f); iB[j] = iA[j];             \
        if (t < NTASK) {                                                    \
            int row = t / 40;                                               \
            int rem = t - row * 40;                                         \
            int q   = rem >> 2;                                             \
            int cp  = rem & 3;                                              \
            int gy  = y0 - RAD + row;                                       \
            int gxb = x0 - 4 + 4 * q;                                       \
            if (gy >= 0 && gy < H && gxb >= 0 && gxb < W) {                 \
                const float* p = inb + (size_t)((g) * 8 + 2 * cp) * HWp     \
                                 + gy * W + gxb;                            \
                iA[j] = *(const float4*)p;                                  \
                iB[j] = *(const float4*)(p + HWp);                          \
            }                                                               \
        }                                                                   \
    }                                                                       \
} while (0)

// ---- pack staged registers and write them to dtu[g] ----
#define WRITE_IN(g) do {                                                    \
    _Pragma("unroll")                                                       \
    for (int j = 0; j < 2; ++j) {                                           \
        int t = tid + j * 512;                                              \
        if (t < NTASK) {                                                    \
            int row = t / 40;                                               \
            int rem = t - row * 40;                                         \
            int q   = rem >> 2;                                             \
            int cp  = rem & 3;                                              \
            int s0  = row * 2 * PAIRS + 2 * q;                              \
            unsigned* dst = &dtu[(g)][cp];                                  \
            if (q != 0) dst[(s0 + PAIRS - 1) * 4] = pk(iA[j].x, iB[j].x);   \
            dst[s0 * 4]           = pk(iA[j].y, iB[j].y);                   \
            dst[(s0 + PAIRS) * 4] = pk(iA[j].z, iB[j].z);                   \
            if (q != 9) dst[(s0 + 1) * 4] = pk(iA[j].w, iB[j].w);           \
        }                                                                   \
    }                                                                       \
} while (0)

// ---- apply group g with the register-resident packed weights ----
#define APPLY(g) do {                                                       \
    const uint4* dg = (const uint4*)&dtu[(g)][0];                           \
    float acc[8];                                                           \
    _Pragma("unroll") for (int c = 0; c < 8; ++c) acc[c] = 0.f;             \
    _Pragma("unroll")                                                       \
    for (int i = 0; i < KS; ++i) {                                          \
        const int rb = (ty + i) * 2 * PAIRS;                                \
        uint4 rq[KS];                                                       \
        _Pragma("unroll")                                                   \
        for (int k = 0; k < KS; ++k) rq[k] = dg[rb + colAdd[k]];            \
        f16x2 A0 = (f16x2)0, A1 = (f16x2)0, A2 = (f16x2)0, A3 = (f16x2)0;   \
        _Pragma("unroll")                                                   \
        for (int k = 0; k < KS; ++k) {                                      \
            f16x2 wh = bch(wkp[i * KS + k]);                                \
            A0 = wh * bch(rq[k].x) + A0;                                    \
            A1 = wh * bch(rq[k].y) + A1;                                    \
            A2 = wh * bch(rq[k].z) + A2;                                    \
            A3 = wh * bch(rq[k].w) + A3;                                    \
        }                                                                   \
        acc[0] += (float)A0.x; acc[1] += (float)A0.y;                       \
        acc[2] += (float)A1.x; acc[3] += (float)A1.y;                       \
        acc[4] += (float)A2.x; acc[5] += (float)A2.y;                       \
        acc[6] += (float)A3.x; acc[7] += (float)A3.y;                       \
    }                                                                       \
    float* ob = out + ((size_t)b * 32 + (g) * 8) * HWp                      \
                + (size_t)Yo * W + Xo;                                      \
    _Pragma("unroll")                                                       \
    for (int c = 0; c < 8; ++c) ob[(size_t)c * HWp] = acc[c] * inv;         \
} while (0)

__global__ __launch_bounds__(512)
void bilateral_kernel(const float* __restrict__ in,      // [B][32][H][W]
                      const float* __restrict__ guide,   // [B][3][H][W]
                      const float* __restrict__ sigma_p, // [1]
                      float* __restrict__ out)           // [B][32][H][W]
{
    // parity-split site: (row,col) -> (row*2 + (col&1))*PAIRS + (col>>1)
    __shared__ uint2 gt2[NSITE];                          // {pk(x~,y~), pk(z~,q~)}
    __shared__ __align__(16) unsigned dtu[4][NSITE * 4];  // 4 grp x 8ch fp16/site

    const int tid = threadIdx.x;
    const int tx  = tid & 31;            // output col 0..31
    const int ty  = tid >> 5;            // output row 0..15
    const int x0  = blockIdx.x * TW;
    const int y0  = blockIdx.y * TH;
    const int b   = blockIdx.z;

    const float* gb  = guide + (size_t)b * 3  * HWp;
    const float* inb = in    + (size_t)b * 32 * HWp;

    const float sigma = sigma_p[0];
    const float isig2 = 1.0f / (sigma * sigma);
    const float L2E   = 1.442695041f;          // log2(e)
    const float SQL   = 1.201122409f;          // sqrt(log2(e))
    float lnT2[KS];
#pragma unroll
    for (int i = 0; i < KS; ++i) {
        float r = (float)(i - RAD);
        lnT2[i] = -0.5f * r * r * isig2 * L2E;
    }

    // ---- phase 0: issue guide loads, then group-0 input loads ----
    float4 gX = make_float4(0.f, 0.f, 0.f, 0.f), gY = gX, gZ = gX;
    int grow = 0, gq = 0;
    if (tid < HR * 10) {
        grow = tid / 10; gq = tid - grow * 10;
        int gy  = y0 - RAD + grow;
        int gxb = x0 - 4 + 4 * gq;                // 4-aligned quad
        if (gy >= 0 && gy < H && gxb >= 0 && gxb < W) {
            const float* p = gb + gy * W + gxb;
            gX = *(const float4*)p;
            gY = *(const float4*)(p + HWp);
            gZ = *(const float4*)(p + 2 * HWp);
        }
    }
    float4 iA[2], iB[2];
    ISSUE_IN(0);                                  // g0 loads fly under guide+weights

    // ---- guide pack + LDS write ----
    if (tid < HR * 10) {
        int s0 = grow * 2 * PAIRS + 2 * gq;
        const float xs[4] = {gX.x, gX.y, gX.z, gX.w};
        const float ys[4] = {gY.x, gY.y, gY.z, gY.w};
        const float zs[4] = {gZ.x, gZ.y, gZ.z, gZ.w};
        const int   st[4] = {s0 + PAIRS - 1, s0, s0 + PAIRS, s0 + 1};
#pragma unroll
        for (int j = 0; j < 4; ++j) {
            if ((gq == 0 && j == 0) || (gq == 9 && j == 3)) continue;
            float ax = xs[j] * SQL, ay = ys[j] * SQL, az = zs[j] * SQL;
            float qv = -0.5f * (ax * ax + ay * ay + az * az);
            gt2[st[j]] = make_uint2(pk(ax, ay), pk(az, qv));
        }
    }
    __syncthreads();                              // gt2 ready

    // ---- per-column site offsets (hoisted) ----
    int colAdd[KS];
#pragma unroll
    for (int k = 0; k < KS; ++k) {
        int col = tx + k;
        colAdd[k] = (col & 1) * PAIRS + (col >> 1);
    }

    // ---- weights (g0 loads in flight underneath) ----
    const int ccol = tx + RAD;
    uint2 cr = gt2[(ty + RAD) * 2 * PAIRS + (ccol & 1) * PAIRS + (ccol >> 1)];
    const f16x2 cxy = bch(cr.x);
    f16x2 czq = bch(cr.y);
    const float qc = (float)czq.y;
    f16x2 cz1;
    cz1.x = czq.x; cz1.y = (_Float16)1.0f;

    unsigned wkp[KS * KS];
    float nsum = 0.f;
#pragma unroll
    for (int i = 0; i < KS; ++i) {
        const int rb = (ty + i) * 2 * PAIRS;
        const float Qi = lnT2[i] + qc;
#pragma unroll
        for (int k = 0; k < KS; ++k) {
            uint2 g = gt2[rb + colAdd[k]];
            float e = fdot2(bch(g.x), cxy, fdot2(bch(g.y), cz1, Qi + lnT2[k]));
            float w = exp2f(e);
            nsum += w;
            wkp[i * KS + k] = pk(w, w);
        }
    }
    const float inv = 1.f / nsum;   // >= center weight ~= 1, never 0
    const int Xo = x0 + tx, Yo = y0 + ty;

    // ---- pipeline: barrier -> [issue g+1 || apply g -> write g+1] ----
    WRITE_IN(0);
    __syncthreads();              // dtu[0] ready
    ISSUE_IN(1);                  // loads fly UNDER apply(0), no barrier between
    APPLY(0);
    WRITE_IN(1);                  // waits vmcnt for g1 data only
    __syncthreads();              // dtu[1] ready
    ISSUE_IN(2);
    APPLY(1);
    WRITE_IN(2);
    __syncthreads();              // dtu[2] ready
    ISSUE_IN(3);
    APPLY(2);
    WRITE_IN(3);
    __syncthreads();              // dtu[3] ready
    APPLY(3);
}

extern "C" void kernel_launch(void* const* d_in, const int* in_sizes, int n_in,
                              void* d_out, int out_size, void* d_ws, size_t ws_size,
                              hipStream_t stream) {
    const float* in    = (const float*)d_in[0];
    const float* guide = (const float*)d_in[1];
    const float* sigma = (const float*)d_in[2];
    float* out = (float*)d_out;
    dim3 grid(W / TW, H / TH, 2);
    bilateral_kernel<<<grid, dim3(512), 0, stream>>>(in, guide, sigma, out);
}

// Round 18
// 22.544 us; speedup vs baseline: 1.0803x; 1.0803x over previous
//
#include <hip/hip_runtime.h>

#define KS    7
#define RAD   3
#define TW    32            // tile width (output px)
#define TH    8             // tile height (halved: 2 independent blocks/CU)
#define HR    14            // halo rows = TH + 2*RAD
#define PAIRS 21            // col-pairs per parity row (19 needed, +2 pad)
#define NSITE (HR*2*PAIRS)  // 588 sites
#define H     256
#define W     256
#define HWp   (H*W)
#define NTASK (HR*10*4)     // 560 input staging tasks per group

typedef __fp16    h2raw __attribute__((ext_vector_type(2)));
typedef _Float16  f16x2 __attribute__((ext_vector_type(2)));

__device__ __forceinline__ unsigned pk(float a, float b) {
    h2raw h = __builtin_amdgcn_cvt_pkrtz(a, b);
    return __builtin_bit_cast(unsigned, h);
}
__device__ __forceinline__ f16x2 bch(unsigned u) {
    return __builtin_bit_cast(f16x2, u);
}

#if __has_builtin(__builtin_amdgcn_fdot2)
__device__ __forceinline__ float fdot2(f16x2 a, f16x2 b, float c) {
    return __builtin_amdgcn_fdot2(a, b, c, false);
}
#else
__device__ __forceinline__ float fdot2(f16x2 a, f16x2 b, float c) {
    return c + (float)a.x * (float)b.x + (float)a.y * (float)b.y;
}
#endif

// ---- issue group g's global loads into registers (no LDS touch) ----
#define ISSUE_IN(g) do {                                                    \
    _Pragma("unroll")                                                       \
    for (int j = 0; j < 3; ++j) {                                           \
        int t = tid + j * 256;                                              \
        iA[j] = make_float4(0.f, 0.f, 0.f, 0.f); iB[j] = iA[j];             \
        if (t < NTASK) {                                                    \
            int row = t / 40;                                               \
            int rem = t - row * 40;                                         \
            int q   = rem >> 2;                                             \
            int cp  = rem & 3;                                              \
            int gy  = y0 - RAD + row;                                       \
            int gxb = x0 - 4 + 4 * q;                                       \
            if (gy >= 0 && gy < H && gxb >= 0 && gxb < W) {                 \
                const float* p = inb + (size_t)((g) * 8 + 2 * cp) * HWp     \
                                 + gy * W + gxb;                            \
                iA[j] = *(const float4*)p;                                  \
                iB[j] = *(const float4*)(p + HWp);                          \
            }                                                               \
        }                                                                   \
    }                                                                       \
} while (0)

// ---- pack staged registers and write them to dtu[g] ----
#define WRITE_IN(g) do {                                                    \
    _Pragma("unroll")                                                       \
    for (int j = 0; j < 3; ++j) {                                           \
        int t = tid + j * 256;                                              \
        if (t < NTASK) {                                                    \
            int row = t / 40;                                               \
            int rem = t - row * 40;                                         \
            int q   = rem >> 2;                                             \
            int cp  = rem & 3;                                              \
            int s0  = row * 2 * PAIRS + 2 * q;                              \
            unsigned* dst = &dtu[(g)][cp];                                  \
            if (q != 0) dst[(s0 + PAIRS - 1) * 4] = pk(iA[j].x, iB[j].x);   \
            dst[s0 * 4]           = pk(iA[j].y, iB[j].y);                   \
            dst[(s0 + PAIRS) * 4] = pk(iA[j].z, iB[j].z);                   \
            if (q != 9) dst[(s0 + 1) * 4] = pk(iA[j].w, iB[j].w);           \
        }                                                                   \
    }                                                                       \
} while (0)

// ---- apply group g with the register-resident packed weights ----
#define APPLY(g) do {                                                       \
    const uint4* dg = (const uint4*)&dtu[(g)][0];                           \
    float acc[8];                                                           \
    _Pragma("unroll") for (int c = 0; c < 8; ++c) acc[c] = 0.f;             \
    _Pragma("unroll")                                                       \
    for (int i = 0; i < KS; ++i) {                                          \
        const int rb = (ty + i) * 2 * PAIRS;                                \
        uint4 rq[KS];                                                       \
        _Pragma("unroll")                                                   \
        for (int k = 0; k < KS; ++k) rq[k] = dg[rb + colAdd[k]];            \
        f16x2 A0 = (f16x2)0, A1 = (f16x2)0, A2 = (f16x2)0, A3 = (f16x2)0;   \
        _Pragma("unroll")                                                   \
        for (int k = 0; k < KS; ++k) {                                      \
            f16x2 wh = bch(wkp[i * KS + k]);                                \
            A0 = wh * bch(rq[k].x) + A0;                                    \
            A1 = wh * bch(rq[k].y) + A1;                                    \
            A2 = wh * bch(rq[k].z) + A2;                                    \
            A3 = wh * bch(rq[k].w) + A3;                                    \
        }                                                                   \
        acc[0] += (float)A0.x; acc[1] += (float)A0.y;                       \
        acc[2] += (float)A1.x; acc[3] += (float)A1.y;                       \
        acc[4] += (float)A2.x; acc[5] += (float)A2.y;                       \
        acc[6] += (float)A3.x; acc[7] += (float)A3.y;                       \
    }                                                                       \
    float* ob = out + ((size_t)b * 32 + (g) * 8) * HWp                      \
                + (size_t)Yo * W + Xo;                                      \
    _Pragma("unroll")                                                       \
    for (int c = 0; c < 8; ++c) ob[(size_t)c * HWp] = acc[c] * inv;         \
} while (0)

__global__ __launch_bounds__(256)
void bilateral_kernel(const float* __restrict__ in,      // [B][32][H][W]
                      const float* __restrict__ guide,   // [B][3][H][W]
                      const float* __restrict__ sigma_p, // [1]
                      float* __restrict__ out)           // [B][32][H][W]
{
    // parity-split site: (row,col) -> (row*2 + (col&1))*PAIRS + (col>>1)
    __shared__ uint2 gt2[NSITE];                          // {pk(x~,y~), pk(z~,q~)}
    __shared__ __align__(16) unsigned dtu[4][NSITE * 4];  // 4 grp x 8ch fp16/site

    const int tid = threadIdx.x;
    const int tx  = tid & 31;            // output col 0..31
    const int ty  = tid >> 5;            // output row 0..7
    const int x0  = blockIdx.x * TW;
    const int y0  = blockIdx.y * TH;
    const int b   = blockIdx.z;

    const float* gb  = guide + (size_t)b * 3  * HWp;
    const float* inb = in    + (size_t)b * 32 * HWp;

    const float sigma = sigma_p[0];
    const float isig2 = 1.0f / (sigma * sigma);
    const float L2E   = 1.442695041f;          // log2(e)
    const float SQL   = 1.201122409f;          // sqrt(log2(e))
    float lnT2[KS];
#pragma unroll
    for (int i = 0; i < KS; ++i) {
        float r = (float)(i - RAD);
        lnT2[i] = -0.5f * r * r * isig2 * L2E;
    }

    // ---- phase 0: guide loads (140 quad-tasks), then group-0 input loads ----
    float4 gX = make_float4(0.f, 0.f, 0.f, 0.f), gY = gX, gZ = gX;
    int grow = 0, gq = 0;
    if (tid < HR * 10) {
        grow = tid / 10; gq = tid - grow * 10;
        int gy  = y0 - RAD + grow;
        int gxb = x0 - 4 + 4 * gq;                // 4-aligned quad
        if (gy >= 0 && gy < H && gxb >= 0 && gxb < W) {
            const float* p = gb + gy * W + gxb;
            gX = *(const float4*)p;
            gY = *(const float4*)(p + HWp);
            gZ = *(const float4*)(p + 2 * HWp);
        }
    }
    float4 iA[3], iB[3];
    ISSUE_IN(0);                                  // g0 loads fly under guide+weights

    // ---- guide pack + LDS write ----
    if (tid < HR * 10) {
        int s0 = grow * 2 * PAIRS + 2 * gq;
        const float xs[4] = {gX.x, gX.y, gX.z, gX.w};
        const float ys[4] = {gY.x, gY.y, gY.z, gY.w};
        const float zs[4] = {gZ.x, gZ.y, gZ.z, gZ.w};
        const int   st[4] = {s0 + PAIRS - 1, s0, s0 + PAIRS, s0 + 1};
#pragma unroll
        for (int j = 0; j < 4; ++j) {
            if ((gq == 0 && j == 0) || (gq == 9 && j == 3)) continue;
            float ax = xs[j] * SQL, ay = ys[j] * SQL, az = zs[j] * SQL;
            float qv = -0.5f * (ax * ax + ay * ay + az * az);
            gt2[st[j]] = make_uint2(pk(ax, ay), pk(az, qv));
        }
    }
    __syncthreads();                              // gt2 ready

    // ---- per-column site offsets (hoisted) ----
    int colAdd[KS];
#pragma unroll
    for (int k = 0; k < KS; ++k) {
        int col = tx + k;
        colAdd[k] = (col & 1) * PAIRS + (col >> 1);
    }

    // ---- weights (g0 loads in flight underneath) ----
    const int ccol = tx + RAD;
    uint2 cr = gt2[(ty + RAD) * 2 * PAIRS + (ccol & 1) * PAIRS + (ccol >> 1)];
    const f16x2 cxy = bch(cr.x);
    f16x2 czq = bch(cr.y);
    const float qc = (float)czq.y;
    f16x2 cz1;
    cz1.x = czq.x; cz1.y = (_Float16)1.0f;

    unsigned wkp[KS * KS];
    float nsum = 0.f;
#pragma unroll
    for (int i = 0; i < KS; ++i) {
        const int rb = (ty + i) * 2 * PAIRS;
        const float Qi = lnT2[i] + qc;
#pragma unroll
        for (int k = 0; k < KS; ++k) {
            uint2 g = gt2[rb + colAdd[k]];
            float e = fdot2(bch(g.x), cxy, fdot2(bch(g.y), cz1, Qi + lnT2[k]));
            float w = exp2f(e);
            nsum += w;
            wkp[i * KS + k] = pk(w, w);
        }
    }
    const float inv = 1.f / nsum;   // >= center weight ~= 1, never 0
    const int Xo = x0 + tx, Yo = y0 + ty;

    // ---- pipeline: barrier -> [issue g+1 || apply g -> write g+1] ----
    WRITE_IN(0);
    __syncthreads();              // dtu[0] ready
    ISSUE_IN(1);                  // loads fly under apply(0)
    APPLY(0);
    WRITE_IN(1);
    __syncthreads();              // dtu[1] ready
    ISSUE_IN(2);
    APPLY(1);
    WRITE_IN(2);
    __syncthreads();              // dtu[2] ready
    ISSUE_IN(3);
    APPLY(2);
    WRITE_IN(3);
    __syncthreads();              // dtu[3] ready
    APPLY(3);
}

extern "C" void kernel_launch(void* const* d_in, const int* in_sizes, int n_in,
                              void* d_out, int out_size, void* d_ws, size_t ws_size,
                              hipStream_t stream) {
    const float* in    = (const float*)d_in[0];
    const float* guide = (const float*)d_in[1];
    const float* sigma = (const float*)d_in[2];
    float* out = (float*)d_out;
    dim3 grid(W / TW, H / TH, 2);   // 8 x 32 x 2 = 512 blocks, 2 per CU
    bilateral_kernel<<<grid, dim3(256), 0, stream>>>(in, guide, sigma, out);
}